// Round 10
// baseline (562.116 us; speedup 1.0000x reference)
//
#include <hip/hip_runtime.h>
#include <hip/hip_bf16.h>

#define NUM_USER 60000
#define NUM_ITEM 40000
#define NN 100000
#define NE 500000
#define DIM 64
#define KF 4
#define SCAN_CHUNK 512
#define NBLK_SCAN ((NN + 1 + SCAN_CHUNK - 1) / SCAN_CHUNK)
// padded slot-count upper bounds (each node rounds up to multiple of 4)
#define NEPU_MAX (NE + 3 * NUM_USER)   // 680000 user-side slots max (+1 sentinel)
#define NEPI_MAX (NE + 3 * NUM_ITEM)   // 620000 item-side slots max

// sum within each 16-lane group (butterfly: all lanes get result)
__device__ __forceinline__ float red16(float v) {
    v += __shfl_xor(v, 1);
    v += __shfl_xor(v, 2);
    v += __shfl_xor(v, 4);
    v += __shfl_xor(v, 8);
    return v;
}

__device__ __forceinline__ float b2f(unsigned short u) {
    return __uint_as_float(((unsigned)u) << 16);
}
__device__ __forceinline__ unsigned short f2b(float x) {
    unsigned u = __float_as_uint(x);
    u = (u + 0x7fffu + ((u >> 16) & 1u)) >> 16;   // RNE
    return (unsigned short)u;
}

__device__ __forceinline__ float4 softmax4(float4 s) {
    float m = fmaxf(fmaxf(s.x, s.y), fmaxf(s.z, s.w));
    float e0 = expf(s.x - m), e1 = expf(s.y - m), e2 = expf(s.z - m), e3 = expf(s.w - m);
    float inv = 1.0f / (e0 + e1 + e2 + e3);
    return make_float4(e0 * inv, e1 * inv, e2 * inv, e3 * inv);
}

// wave per node: ego(bf16) = concat(user,item); allemb(fp32); T(bf16) = tanh(l2n16)
__global__ void k_init_tanh(const float* __restrict__ user, const float* __restrict__ item,
                            unsigned short* __restrict__ ego, float* __restrict__ allemb,
                            unsigned short* __restrict__ T) {
    int node = (blockIdx.x * blockDim.x + threadIdx.x) >> 6;
    int lane = threadIdx.x & 63;
    if (node >= NN) return;
    int i = node * DIM + lane;
    float v = (node < NUM_USER) ? user[i] : item[i - NUM_USER * DIM];
    ego[i] = f2b(v);
    allemb[i] = v;
    float ss = red16(v * v);
    T[i] = f2b(tanhf(v / fmaxf(sqrtf(ss), 1e-12f)));
}

__global__ void k_count(const int* __restrict__ row0, const int* __restrict__ col0,
                        int* __restrict__ cnt) {
    int e = blockIdx.x * blockDim.x + threadIdx.x;
    if (e >= NE) return;
    atomicAdd(&cnt[row0[e]], 1);
    atomicAdd(&cnt[col0[e]], 1);
}

// scan1 over padded counts ((d+3)&~3), also emits dinv from raw counts
__global__ void k_scan1(const int* __restrict__ cnt, int* __restrict__ ptr,
                        int* __restrict__ bsum, float* __restrict__ dinv) {
    __shared__ int sm[SCAN_CHUNK];
    int tid = threadIdx.x;
    int idx = blockIdx.x * SCAN_CHUNK + tid;
    int d = (idx < NN) ? cnt[idx] : 0;
    if (idx < NN) dinv[idx] = (d > 0) ? rsqrtf((float)d) : 0.0f;
    int x = (d + 3) & ~3;
    sm[tid] = x;
    __syncthreads();
    for (int off = 1; off < SCAN_CHUNK; off <<= 1) {
        int v = (tid >= off) ? sm[tid - off] : 0;
        __syncthreads();
        sm[tid] += v;
        __syncthreads();
    }
    if (idx <= NN) ptr[idx] = sm[tid] - x;
    if (tid == SCAN_CHUNK - 1) bsum[blockIdx.x] = sm[tid];
}

__global__ void k_scan2(int* __restrict__ bsum, int* __restrict__ offs) {
    __shared__ int sm[256];
    int tid = threadIdx.x;
    int x = (tid < NBLK_SCAN) ? bsum[tid] : 0;
    sm[tid] = x;
    __syncthreads();
    for (int off = 1; off < 256; off <<= 1) {
        int v = (tid >= off) ? sm[tid - off] : 0;
        __syncthreads();
        sm[tid] += v;
        __syncthreads();
    }
    if (tid < NBLK_SCAN) offs[tid] = sm[tid] - x;
}

// finalize ptr and emit the atomic-fill cursor array pos
__global__ void k_scan3(int* __restrict__ ptr, const int* __restrict__ offs,
                        int* __restrict__ pos) {
    int idx = blockIdx.x * blockDim.x + threadIdx.x;
    if (idx <= NN) {
        int v = ptr[idx] + offs[idx / SCAN_CHUNK];
        ptr[idx] = v;
        pos[idx] = v;
    }
}

// fill CSR. user-side slots are [0, ptr[NUM_USER]); edge id := user-side slot j1.
__global__ void k_fill(const int* __restrict__ row0, const int* __restrict__ col0,
                       int* __restrict__ pos, const int* __restrict__ ptr,
                       int* __restrict__ srcadj, int* __restrict__ eitem,
                       int* __restrict__ jpos1) {
    int e = blockIdx.x * blockDim.x + threadIdx.x;
    if (e >= NE) return;
    int r = row0[e], c = col0[e];
    int ptrU = ptr[NUM_USER];
    int j1 = atomicAdd(&pos[r], 1);   // user-side slot: dst=r, src=c
    srcadj[j1] = c;
    jpos1[e] = j1;
    int j0 = atomicAdd(&pos[c], 1);   // item-side slot: dst=c, src=r
    srcadj[j0] = r;
    eitem[j0 - ptrU] = j1;
}

// dummy (padding) slots: src=0; user dummies get normu=0, wA=0;
// item dummies point at zeroed sentinel weight slot (both w buffers)
__global__ void k_pad(const int* __restrict__ cnt, const int* __restrict__ ptr,
                      int* __restrict__ srcadj, int* __restrict__ eitem,
                      float* __restrict__ normu, float4* __restrict__ wA,
                      float4* __restrict__ wB) {
    int n = blockIdx.x * blockDim.x + threadIdx.x;
    if (n >= NN) return;
    int realend = ptr[n] + cnt[n];
    int end = ptr[n + 1];
    int ptrU = ptr[NUM_USER];
    float4 z = make_float4(0.f, 0.f, 0.f, 0.f);
    for (int j = realend; j < end; ++j) {
        srcadj[j] = 0;
        if (n >= NUM_USER) {
            eitem[j - ptrU] = NEPU_MAX;   // sentinel: w=0
        } else {
            normu[j] = 0.0f;
            wA[j] = z;
        }
    }
    if (n == 0) {
        normu[NEPU_MAX] = 0.0f;
        wA[NEPU_MAX] = z;
        wB[NEPU_MAX] = z;
    }
}

// permute S into slot order, norm per slot, initial weights (real slots)
__global__ void k_w0(const float* __restrict__ Sin, const int* __restrict__ row0,
                     const int* __restrict__ col0, const int* __restrict__ jpos1,
                     const float* __restrict__ dinv, float4* __restrict__ Scur4,
                     float* __restrict__ normu, float4* __restrict__ w0) {
    int e = blockIdx.x * blockDim.x + threadIdx.x;
    if (e >= NE) return;
    int j = jpos1[e];
    float n = dinv[row0[e]] * dinv[col0[e]];
    float4 s = make_float4(Sin[e], Sin[NE + e], Sin[2 * NE + e], Sin[3 * NE + e]);
    float4 p = softmax4(s);
    Scur4[j] = s;
    normu[j] = n;
    w0[j] = make_float4(n * p.x, n * p.y, n * p.z, n * p.w);
}

// Scur4 (slot order, already fully updated) -> Sout [4][E] original edge order
__global__ void k_sout(const float4* __restrict__ Scur4, const int* __restrict__ jpos1,
                       float* __restrict__ Sout) {
    int e = blockIdx.x * blockDim.x + threadIdx.x;
    if (e >= NE) return;
    float4 s = Scur4[jpos1[e]];
    Sout[e] = s.x;
    Sout[NE + e] = s.y;
    Sout[2 * NE + e] = s.z;
    Sout[3 * NE + e] = s.w;
}

// fused conv + score + S-update + next-weight. wave per node; branch-free x4
// loops (degree padded to multiple of 4). lane = dim, factor g = lane>>4.
// score epilogue: after 4 red16 butterflies every lane holds p(edge j+m, its
// factor) for m=0..3; a 4x4 cross-group shuffle gives group g the full
// p-vector of edge j+g; group g then does snew=softmax4(S4[j+g])+p4 in place
// and wnext[j+g]=normu*softmax4(snew). S4 slots are owner-exclusive (no race);
// wnext is the ping-pong partner of wcur (item waves gather wcur only).
// flags: 1 = layer end (allemb += acc), 2 = write Twrite, 4 = write xnext,
//        8 = last iteration (skip wnext)
__global__ __launch_bounds__(256) void k_conv_score(
        const int* __restrict__ ptr, const int* __restrict__ srcadj,
        const int* __restrict__ eitem, const float* __restrict__ wcur,
        float4* __restrict__ wnext, const float* __restrict__ normu,
        float4* __restrict__ S4, const unsigned short* __restrict__ ego,
        const unsigned short* __restrict__ Tread, unsigned short* __restrict__ Twrite,
        unsigned short* __restrict__ xnext, float* __restrict__ allemb, int flags) {
    int node = (blockIdx.x * blockDim.x + threadIdx.x) >> 6;
    int lane = threadIdx.x & 63;
    if (node >= NN) return;
    int beg = __builtin_amdgcn_readfirstlane(ptr[node]);
    int end = __builtin_amdgcn_readfirstlane(ptr[node + 1]);
    int g = lane >> 4;

    float a0 = 0.0f, a1 = 0.0f, a2 = 0.0f, a3 = 0.0f;
    if (node < NUM_USER) {
        for (int j = beg; j < end; j += 4) {
            int4 s = *(const int4*)(srcadj + j);
            float w0 = wcur[4 * j + g], w1 = wcur[4 * j + 4 + g];
            float w2 = wcur[4 * j + 8 + g], w3 = wcur[4 * j + 12 + g];
            a0 = fmaf(w0, b2f(ego[s.x * DIM + lane]), a0);
            a1 = fmaf(w1, b2f(ego[s.y * DIM + lane]), a1);
            a2 = fmaf(w2, b2f(ego[s.z * DIM + lane]), a2);
            a3 = fmaf(w3, b2f(ego[s.w * DIM + lane]), a3);
        }
    } else {
        int ptrU = __builtin_amdgcn_readfirstlane(ptr[NUM_USER]);
        for (int j = beg; j < end; j += 4) {
            int4 s = *(const int4*)(srcadj + j);
            int4 e4 = *(const int4*)(eitem + (j - ptrU));
            float w0 = wcur[4 * e4.x + g], w1 = wcur[4 * e4.y + g];
            float w2 = wcur[4 * e4.z + g], w3 = wcur[4 * e4.w + g];
            a0 = fmaf(w0, b2f(ego[s.x * DIM + lane]), a0);
            a1 = fmaf(w1, b2f(ego[s.y * DIM + lane]), a1);
            a2 = fmaf(w2, b2f(ego[s.z * DIM + lane]), a2);
            a3 = fmaf(w3, b2f(ego[s.w * DIM + lane]), a3);
        }
    }
    float acc = (a0 + a1) + (a2 + a3);

    if (flags & 1) {
        int i = node * DIM + lane;
        allemb[i] += acc;
        if (flags & 4) xnext[i] = f2b(acc);
        if (flags & 2) {
            float ss = red16(acc * acc);
            Twrite[i] = f2b(tanhf(acc / fmaxf(sqrtf(ss), 1e-12f)));
        }
    }

    if (node >= NUM_USER) return;

    // ---- score + S update + next weights ----
    float ssu = red16(acc * acc);
    float u = acc / fmaxf(sqrtf(ssu), 1e-12f);
    int m = lane & 3;
    bool lead = (lane & 15) == 0;
    int last = flags & 8;
    for (int j = beg; j < end; j += 4) {
        int4 s = *(const int4*)(srcadj + j);
        float p0 = red16(u * b2f(Tread[s.x * DIM + lane]));
        float p1 = red16(u * b2f(Tread[s.y * DIM + lane]));
        float p2 = red16(u * b2f(Tread[s.z * DIM + lane]));
        float p3 = red16(u * b2f(Tread[s.w * DIM + lane]));
        // transpose: present p_{lane&3}; dest (group g) pulls from lane f*16+g
        float q = (m == 0) ? p0 : (m == 1) ? p1 : (m == 2) ? p2 : p3;
        float pf0 = __shfl(q, 0 * 16 + g);
        float pf1 = __shfl(q, 1 * 16 + g);
        float pf2 = __shfl(q, 2 * 16 + g);
        float pf3 = __shfl(q, 3 * 16 + g);
        int je = j + g;                      // group g owns edge j+g
        float4 sm = softmax4(S4[je]);
        float4 snew = make_float4(sm.x + pf0, sm.y + pf1, sm.z + pf2, sm.w + pf3);
        if (lead) S4[je] = snew;             // in-place: owner-exclusive slot
        if (!last) {
            float4 qq = softmax4(snew);
            float n = normu[je];
            if (lead) wnext[je] = make_float4(n * qq.x, n * qq.y, n * qq.z, n * qq.w);
        }
    }
}

extern "C" void kernel_launch(void* const* d_in, const int* in_sizes, int n_in,
                              void* d_out, int out_size, void* d_ws, size_t ws_size,
                              hipStream_t stream) {
    const float* user = (const float*)d_in[0];
    const float* item = (const float*)d_in[1];
    const float* S_in = (const float*)d_in[2];
    const int* edge = (const int*)d_in[3];
    const int* row0 = edge;
    const int* col0 = edge + NE;

    float* out = (float*)d_out;
    float* allemb = out;              // NN*DIM floats
    float* Sfinal = out + NN * DIM;   // KF*NE floats

    char* ws = (char*)d_ws;
    size_t off = 0;
    auto carve = [&](size_t bytes) { void* p = ws + off; off += (bytes + 255) & ~(size_t)255; return p; };
    int* cnt = (int*)carve((NN + 1) * sizeof(int));
    int* ptr = (int*)carve((NN + 1) * sizeof(int));
    int* pos = (int*)carve((NN + 1) * sizeof(int));
    int* bsum = (int*)carve(256 * sizeof(int));
    int* offs = (int*)carve(256 * sizeof(int));
    int* srcadj = (int*)carve((size_t)(NEPU_MAX + NEPI_MAX) * sizeof(int));
    int* eitem = (int*)carve((size_t)NEPI_MAX * sizeof(int));
    int* jpos1 = (int*)carve((size_t)NE * sizeof(int));
    float* dinv = (float*)carve(NN * sizeof(float));
    float* normu = (float*)carve((size_t)(NEPU_MAX + 1) * sizeof(float));
    float4* Scur4 = (float4*)carve((size_t)(NEPU_MAX + 1) * sizeof(float4));
    float4* wA = (float4*)carve((size_t)(NEPU_MAX + 1) * sizeof(float4));
    float4* wB = (float4*)carve((size_t)(NEPU_MAX + 1) * sizeof(float4));
    unsigned short* egoA = (unsigned short*)carve((size_t)NN * DIM * 2);
    unsigned short* egoB = (unsigned short*)carve((size_t)NN * DIM * 2);
    unsigned short* TA = (unsigned short*)carve((size_t)NN * DIM * 2);
    unsigned short* TB = (unsigned short*)carve((size_t)NN * DIM * 2);

    hipMemsetAsync(cnt, 0, (NN + 1) * sizeof(int), stream);

    k_count<<<(NE + 255) / 256, 256, 0, stream>>>(row0, col0, cnt);
    k_scan1<<<NBLK_SCAN, SCAN_CHUNK, 0, stream>>>(cnt, ptr, bsum, dinv);
    k_scan2<<<1, 256, 0, stream>>>(bsum, offs);
    k_scan3<<<(NN + 1 + 255) / 256, 256, 0, stream>>>(ptr, offs, pos);
    k_fill<<<(NE + 255) / 256, 256, 0, stream>>>(row0, col0, pos, ptr, srcadj, eitem, jpos1);
    k_pad<<<(NN + 255) / 256, 256, 0, stream>>>(cnt, ptr, srcadj, eitem, normu, wA, wB);
    k_w0<<<(NE + 255) / 256, 256, 0, stream>>>(S_in, row0, col0, jpos1, dinv,
                                               Scur4, normu, wA);
    k_init_tanh<<<(NN * 64 + 255) / 256, 256, 0, stream>>>(user, item, egoA, allemb, TA);

    unsigned short* ego = egoA;
    unsigned short* xn = egoB;
    unsigned short* Trd = TA;
    unsigned short* Twr = TB;
    float4* wcur = wA;
    float4* wnx = wB;
    for (int layer = 0; layer < 2; ++layer) {
        for (int it = 0; it < 2; ++it) {
            int flags = 0;
            if (it == 1) flags |= 1;                   // layer end: allemb += acc
            if (it == 1 && layer == 0) flags |= 2 | 4; // write T + next ego
            if (layer == 1 && it == 1) flags |= 8;     // last: skip wnext
            k_conv_score<<<(NN * 64 + 255) / 256, 256, 0, stream>>>(
                ptr, srcadj, eitem, (const float*)wcur, wnx, normu,
                Scur4, ego, Trd, Twr, xn, allemb, flags);
            float4* tw = wcur; wcur = wnx; wnx = tw;
        }
        unsigned short* t = ego; ego = xn; xn = t;
        t = Trd; Trd = Twr; Twr = t;
    }
    k_sout<<<(NE + 255) / 256, 256, 0, stream>>>(Scur4, jpos1, Sfinal);
}